// Round 1
// baseline (234.592 us; speedup 1.0000x reference)
//
#include <hip/hip_runtime.h>
#include <hip/hip_bf16.h>

#define NN 10000
#define EE 640000
#define CIN 128
#define COUT 128
#define HH 256
#define SLOT 160
#define BN_EPS 1e-5f
#define XPITCH 136   // shorts per staged x row (+8 pad) in stage1
#define HPITCH 320   // shorts per hbuf row (640 B pitch, staircase-swizzled)

typedef __attribute__((ext_vector_type(8))) short short8x;
typedef __attribute__((ext_vector_type(4))) float floatx4;
typedef __attribute__((ext_vector_type(16))) float floatx16;

// Static device scratch (re-initialized every launch; graph-capture safe).
__device__ float          g_A[NN * HH];            // fp32 node term A = xn@(W1t-W1b)+b1
__device__ unsigned short g_Bb[NN * HH];           // bf16 node term B = xn@W1b
__device__ int            g_cnt[NN];               // per-node edge count
__device__ int            g_slots[NN * SLOT + 64]; // src ids, slotted by dst
__device__ unsigned short g_W2f[4 * 16 * 64 * 8];  // W2 bf16, 32x32x16 B-frag order
__device__ unsigned short g_W1f[32 * 4 * 64 * 8];  // [W1t-W1b | W1b] bf16, B-frag order

__device__ __forceinline__ unsigned short f2bf(float f) {
    unsigned u = __float_as_uint(f);
    u += 0x7fffu + ((u >> 16) & 1u);   // RNE
    return (unsigned short)(u >> 16);
}
__device__ __forceinline__ float bf2f(unsigned short h) {
    return __uint_as_float(((unsigned)h) << 16);
}
// Packed f32x2 -> bf16x2 (v_cvt_pk_bf16_f32 on gfx950).
__device__ __forceinline__ unsigned pkbf(float a, float b) {
    __hip_bfloat162 t = __float22bfloat162_rn(make_float2(a, b));
    union { __hip_bfloat162 h; unsigned u; } cv; cv.h = t;
    return cv.u;
}

// Merged prep: zero g_cnt, swizzle W2 (32x32x16 B-frag order), fold+swizzle W1.
__global__ void prep_kernel(const float* __restrict__ W1, const float* __restrict__ W2) {
    const int b = blockIdx.x, tid = threadIdx.x;
    if (b < 40) {
        int i = b * 256 + tid;
        if (i < NN) g_cnt[i] = 0;
        return;
    }
    if (b < 56) {
        int idx = (b - 40) * 256 + tid;        // 0..4095
        int lane = idx & 63;
        int l31 = lane & 31, half = lane >> 5;
        int rest = idx >> 6;                   // 0..63
        int k0 = rest & 15, cg = rest >> 4;
        unsigned short frag[8];
        #pragma unroll
        for (int j = 0; j < 8; j++)
            frag[j] = f2bf(W2[(k0 * 16 + half * 8 + j) * COUT + cg * 32 + l31]);
        *(short8x*)(g_W2f + (size_t)idx * 8) = *(short8x*)frag;
        return;
    }
    int idx = (b - 56) * 256 + tid;            // 0..8191
    int lane = idx & 63;
    int quad = lane >> 4, m = lane & 15;
    int t = idx >> 8, k0 = (idx >> 6) & 3;
    int c = t * 16 + m;                        // global col 0..511
    unsigned short frag[8];
    #pragma unroll
    for (int j = 0; j < 8; j++) {
        int k = k0 * 32 + quad * 8 + j;
        float v = (c < 256) ? (W1[k * HH + c] - W1[(k + CIN) * HH + c])
                            : W1[(k + CIN) * HH + (c - 256)];
        frag[j] = f2bf(v);
    }
    *(short8x*)(g_W1f + (size_t)idx * 8) = *(short8x*)frag;
}

// Stage 1 via MFMA: [A|B] = (xh+xl) @ W1f, 32 nodes/block.
__global__ __launch_bounds__(256) void stage1_kernel(
    const float* __restrict__ x, const float* __restrict__ gamma,
    const float* __restrict__ beta, const float* __restrict__ mean,
    const float* __restrict__ var, const float* __restrict__ b1)
{
    __shared__ unsigned short xh[32 * XPITCH];
    __shared__ unsigned short xl[32 * XPITCH];
    __shared__ float s_lds[CIN], t_lds[CIN];
    const int tid = threadIdx.x;
    const int w = tid >> 6, lane = tid & 63;
    const int m = lane & 15, quad = lane >> 4;
    if (tid < CIN) {
        float s = gamma[tid] * rsqrtf(var[tid] + BN_EPS);
        s_lds[tid] = s;
        t_lds[tid] = beta[tid] - mean[tid] * s;
    }
    __syncthreads();
    const int mbase = blockIdx.x * 32;
    #pragma unroll
    for (int it = 0; it < 4; it++) {
        int slot = it * 256 + tid;
        int n = slot >> 5;
        int k = (slot & 31) * 4;
        int node = mbase + n;
        float4 v = make_float4(0.f, 0.f, 0.f, 0.f);
        if (node < NN) v = *(const float4*)(x + (size_t)node * CIN + k);
        float f[4] = {v.x, v.y, v.z, v.w};
        ushort4 uh, ul;
        unsigned short hb;
        float fn;
        fn = f[0] * s_lds[k + 0] + t_lds[k + 0]; hb = f2bf(fn); uh.x = hb; ul.x = f2bf(fn - bf2f(hb));
        fn = f[1] * s_lds[k + 1] + t_lds[k + 1]; hb = f2bf(fn); uh.y = hb; ul.y = f2bf(fn - bf2f(hb));
        fn = f[2] * s_lds[k + 2] + t_lds[k + 2]; hb = f2bf(fn); uh.z = hb; ul.z = f2bf(fn - bf2f(hb));
        fn = f[3] * s_lds[k + 3] + t_lds[k + 3]; hb = f2bf(fn); uh.w = hb; ul.w = f2bf(fn - bf2f(hb));
        *(ushort4*)(xh + n * XPITCH + k) = uh;
        *(ushort4*)(xl + n * XPITCH + k) = ul;
    }
    __syncthreads();

    floatx4 acc[2][8];
    #pragma unroll
    for (int mt = 0; mt < 2; mt++)
        #pragma unroll
        for (int nt = 0; nt < 8; nt++)
            acc[mt][nt] = (floatx4){0.f, 0.f, 0.f, 0.f};

    #pragma unroll
    for (int k0 = 0; k0 < 4; k0++) {
        short8x wf[8];
        #pragma unroll
        for (int nt = 0; nt < 8; nt++) {
            int t = w * 8 + nt;
            wf[nt] = *(const short8x*)(g_W1f + (size_t)((t * 4 + k0) * 64 + lane) * 8);
        }
        #pragma unroll
        for (int mt = 0; mt < 2; mt++) {
            const unsigned short* rp = xh + (mt * 16 + m) * XPITCH + k0 * 32 + quad * 8;
            const unsigned short* lp = xl + (mt * 16 + m) * XPITCH + k0 * 32 + quad * 8;
            short8x ah = *(const short8x*)rp;
            short8x al = *(const short8x*)lp;
            #pragma unroll
            for (int nt = 0; nt < 8; nt++) {
                acc[mt][nt] = __builtin_amdgcn_mfma_f32_16x16x32_bf16(al, wf[nt], acc[mt][nt], 0, 0, 0);
                acc[mt][nt] = __builtin_amdgcn_mfma_f32_16x16x32_bf16(ah, wf[nt], acc[mt][nt], 0, 0, 0);
            }
        }
    }
    const int colbase = w * 128;
    #pragma unroll
    for (int mt = 0; mt < 2; mt++) {
        #pragma unroll
        for (int nt = 0; nt < 8; nt++) {
            int col = colbase + nt * 16 + m;
            #pragma unroll
            for (int j = 0; j < 4; j++) {
                int node = mbase + mt * 16 + quad * 4 + j;
                if (node < NN) {
                    float v = acc[mt][nt][j];
                    if (col < 256) g_A[(size_t)node * HH + col] = v + b1[col];
                    else           g_Bb[(size_t)node * HH + (col - 256)] = f2bf(v);
                }
            }
        }
    }
}

// Single-pass slot scatter, 4 edges/thread (int4 loads).
__global__ void scatter_kernel(const int* __restrict__ ei) {
    int t = blockIdx.x * 256 + threadIdx.x;
    int e = t * 4;
    if (e < EE) {
        int4 s4 = *(const int4*)(ei + e);
        int4 d4 = *(const int4*)(ei + EE + e);
        int p;
        p = atomicAdd(&g_cnt[d4.x], 1); if (p < SLOT) g_slots[d4.x * SLOT + p] = s4.x;
        p = atomicAdd(&g_cnt[d4.y], 1); if (p < SLOT) g_slots[d4.y * SLOT + p] = s4.y;
        p = atomicAdd(&g_cnt[d4.z], 1); if (p < SLOT) g_slots[d4.z * SLOT + p] = s4.z;
        p = atomicAdd(&g_cnt[d4.w], 1); if (p < SLOT) g_slots[d4.w * SLOT + p] = s4.w;
    }
}

// Main kernel v2: 512 threads = 8 waves; 64-edge periods; 32x32x16 MFMA.
// Wave w: m-tile mt=w>>2 (rows mt*32..mt*32+31), col-group cg=w&3 (cols cg*32..+31).
// Wave w also PRODUCES h rows w*8..w*8+7 (aligned with its own m-tile -> wave-uniform
// skip of fully-padded tiles). hbuf uses 640B pitch + affine staircase (+ (row&7)*16B):
// producer writes stay a contiguous 512B window per row; consumer ds_read_b128
// fragment reads land exactly 8 lanes per bank-group (wave64/b128 minimum).
__global__ __launch_bounds__(512, 4) void edge_kernel(const float* __restrict__ b2,
                                                      float* __restrict__ out)
{
    __shared__ unsigned short hbuf[64 * HPITCH];   // 40 KB
    __shared__ int sbuf[SLOT];
    __shared__ float smax[128];
    const int tid = threadIdx.x;
    const int w = tid >> 6, lane = tid & 63;
    const int l31 = lane & 31, half = lane >> 5;
    const int cg = w & 3, mt = w >> 2;
    const unsigned laneoff = (unsigned)lane << 3;  // lane*8 bytes

    // Full-K W2 B-frags for col-group cg: 16 x short8x = 64 VGPR.
    short8x bfrag[16];
    #pragma unroll
    for (int k0 = 0; k0 < 16; k0++)
        bfrag[k0] = *(const short8x*)(g_W2f + (size_t)(((cg * 16 + k0) * 64 + lane)) * 8);
    const float b2v = b2[cg * 32 + l31];

    for (int g = 0; g < 4; g++) {
        const int node = blockIdx.x * 4 + g;
        int deg = g_cnt[node]; if (deg > SLOT) deg = SLOT;
        const float4 av = *(const float4*)(g_A + (size_t)node * HH + lane * 4);
        if (tid < deg) sbuf[tid] = g_slots[node * SLOT + tid];
        __syncthreads();                  // sbuf ready; prev node done with smax/hbuf
        float rm = -INFINITY;
        if (deg > 0) {
            const int ntp = (deg + 63) >> 6;
            uint2 bv[8];
            if (mt * 32 < deg) {          // prefetch period 0 (own tile active)
                #pragma unroll
                for (int q = 0; q < 8; q++) {
                    int er = w * 8 + q;
                    int sv = (er < deg) ? sbuf[er] : 0;
                    bv[q] = *(const uint2*)((const char*)g_Bb + (((unsigned)sv << 9) | laneoff));
                }
            }
            for (int p = 0; p < ntp; p++) {
                const int tb = p << 6;
                const bool act = (tb + mt * 32) < deg;   // wave-uniform tile-valid
                if (act) {
                    #pragma unroll
                    for (int q = 0; q < 8; q++) {
                        uint2 b = bv[q];
                        float f0 = __uint_as_float(b.x << 16);
                        float f1 = __uint_as_float(b.x & 0xffff0000u);
                        float f2 = __uint_as_float(b.y << 16);
                        float f3 = __uint_as_float(b.y & 0xffff0000u);
                        uint2 hv;
                        hv.x = pkbf(fmaxf(av.x + f0, 0.f), fmaxf(av.y + f1, 0.f));
                        hv.y = pkbf(fmaxf(av.z + f2, 0.f), fmaxf(av.w + f3, 0.f));
                        // row = w*8+q; (row&7)==q -> staircase is compile-time per q
                        *(uint2*)(hbuf + (w * 8 + q) * HPITCH + (q << 3) + (lane << 2)) = hv;
                    }
                }
                __syncthreads();          // hbuf(p) ready
                const int tb2 = tb + 64;
                if (tb2 + mt * 32 < deg) {   // prefetch next period during MFMA
                    #pragma unroll
                    for (int q = 0; q < 8; q++) {
                        int er = tb2 + w * 8 + q;
                        int sv = (er < deg) ? sbuf[er] : 0;
                        bv[q] = *(const uint2*)((const char*)g_Bb + (((unsigned)sv << 9) | laneoff));
                    }
                }
                if (act) {
                    const int row = mt * 32 + l31;
                    const unsigned short* ha = hbuf + row * HPITCH + ((l31 & 7) << 3) + (half << 3);
                    floatx16 acc;
                    #pragma unroll
                    for (int j = 0; j < 16; j++) acc[j] = 0.f;
                    #pragma unroll
                    for (int k0 = 0; k0 < 16; k0++) {
                        short8x af = *(const short8x*)(ha + k0 * 16);
                        acc = __builtin_amdgcn_mfma_f32_32x32x16_bf16(af, bfrag[k0], acc, 0, 0, 0);
                    }
                    const int rowb = tb + mt * 32;
                    if (rowb + 32 <= deg) {
                        #pragma unroll
                        for (int j = 0; j < 16; j++) rm = fmaxf(rm, acc[j]);
                    } else {
                        #pragma unroll
                        for (int j = 0; j < 16; j++) {
                            int rr = rowb + (j & 3) + ((j >> 2) << 3) + (half << 2);
                            if (rr < deg) rm = fmaxf(rm, acc[j]);
                        }
                    }
                }
                __syncthreads();          // all waves done reading hbuf(p)
            }
        }
        // rows split across half -> combine; then combine the two m-tile groups.
        rm = fmaxf(rm, __shfl_xor(rm, 32));
        if (w >= 4 && lane < 32) smax[cg * 32 + lane] = rm;
        __syncthreads();
        if (w < 4 && lane < 32) {
            float v = fmaxf(rm, smax[cg * 32 + lane]);
            out[(size_t)node * COUT + cg * 32 + lane] = (deg > 0) ? fmaxf(v + b2v, 0.f) : 0.f;
        }
    }
}

extern "C" void kernel_launch(void* const* d_in, const int* in_sizes, int n_in,
                              void* d_out, int out_size, void* d_ws, size_t ws_size,
                              hipStream_t stream) {
    const float* x      = (const float*)d_in[0];
    const int*   ei     = (const int*)d_in[1];
    const float* gamma  = (const float*)d_in[2];
    const float* beta   = (const float*)d_in[3];
    const float* mean   = (const float*)d_in[4];
    const float* var    = (const float*)d_in[5];
    const float* W1     = (const float*)d_in[6];
    const float* b1     = (const float*)d_in[7];
    const float* W2     = (const float*)d_in[8];
    const float* b2     = (const float*)d_in[9];
    float* out = (float*)d_out;
    (void)d_ws; (void)ws_size;

    prep_kernel<<<88, 256, 0, stream>>>(W1, W2);
    stage1_kernel<<<(NN + 31) / 32, 256, 0, stream>>>(x, gamma, beta, mean, var, b1);
    scatter_kernel<<<(EE / 4 + 255) / 256, 256, 0, stream>>>(ei);
    edge_kernel<<<NN / 4, 512, 0, stream>>>(b2, out);
}

// Round 2
// 199.825 us; speedup vs baseline: 1.1740x; 1.1740x over previous
//
#include <hip/hip_runtime.h>
#include <hip/hip_bf16.h>

#define NN 10000
#define EE 640000
#define CIN 128
#define COUT 128
#define HH 256
#define SLOT 160
#define BN_EPS 1e-5f
#define XPITCH 136   // shorts per staged x row (+8 pad) in stage1
#define HPITCH 264   // shorts per hbuf row (528 B pitch: 132 words == 4 mod 32)
#define S1BLOCKS 313 // (NN+31)/32

typedef __attribute__((ext_vector_type(8))) short short8x;
typedef __attribute__((ext_vector_type(4))) float floatx4;
typedef __attribute__((ext_vector_type(16))) float floatx16;

// Static device scratch (re-initialized every launch; graph-capture safe).
__device__ float          g_A[NN * HH];            // fp32 node term A = xn@(W1t-W1b)+b1
__device__ unsigned short g_Bb[NN * HH];           // bf16 node term B = xn@W1b
__device__ int            g_cnt[NN];               // per-node edge count
__device__ int            g_slots[NN * SLOT + 64]; // src ids, slotted by dst
__device__ unsigned short g_W2f[4 * 16 * 64 * 8];  // W2 bf16, 32x32x16 B-frag order
__device__ unsigned short g_W1f[32 * 4 * 64 * 8];  // [W1t-W1b | W1b] bf16, B-frag order

__device__ __forceinline__ unsigned short f2bf(float f) {
    unsigned u = __float_as_uint(f);
    u += 0x7fffu + ((u >> 16) & 1u);   // RNE
    return (unsigned short)(u >> 16);
}
__device__ __forceinline__ float bf2f(unsigned short h) {
    return __uint_as_float(((unsigned)h) << 16);
}
// Packed f32x2 -> bf16x2 (v_cvt_pk_bf16_f32 on gfx950).
__device__ __forceinline__ unsigned pkbf(float a, float b) {
    __hip_bfloat162 t = __float22bfloat162_rn(make_float2(a, b));
    union { __hip_bfloat162 h; unsigned u; } cv; cv.h = t;
    return cv.u;
}

// Merged prep: zero g_cnt, swizzle W2 (32x32x16 B-frag order), fold+swizzle W1.
__global__ void prep_kernel(const float* __restrict__ W1, const float* __restrict__ W2) {
    const int b = blockIdx.x, tid = threadIdx.x;
    if (b < 40) {
        int i = b * 256 + tid;
        if (i < NN) g_cnt[i] = 0;
        return;
    }
    if (b < 56) {
        int idx = (b - 40) * 256 + tid;        // 0..4095
        int lane = idx & 63;
        int l31 = lane & 31, half = lane >> 5;
        int rest = idx >> 6;                   // 0..63
        int k0 = rest & 15, cg = rest >> 4;
        unsigned short frag[8];
        #pragma unroll
        for (int j = 0; j < 8; j++)
            frag[j] = f2bf(W2[(k0 * 16 + half * 8 + j) * COUT + cg * 32 + l31]);
        *(short8x*)(g_W2f + (size_t)idx * 8) = *(short8x*)frag;
        return;
    }
    int idx = (b - 56) * 256 + tid;            // 0..8191
    int lane = idx & 63;
    int quad = lane >> 4, m = lane & 15;
    int t = idx >> 8, k0 = (idx >> 6) & 3;
    int c = t * 16 + m;                        // global col 0..511
    unsigned short frag[8];
    #pragma unroll
    for (int j = 0; j < 8; j++) {
        int k = k0 * 32 + quad * 8 + j;
        float v = (c < 256) ? (W1[k * HH + c] - W1[(k + CIN) * HH + c])
                            : W1[(k + CIN) * HH + (c - 256)];
        frag[j] = f2bf(v);
    }
    *(short8x*)(g_W1f + (size_t)idx * 8) = *(short8x*)frag;
}

// Fused: blocks [0,S1BLOCKS) run stage1 (MFMA: [A|B] = xn @ W1f, 32 nodes/block);
// blocks [S1BLOCKS, S1BLOCKS+625) run the edge-slot scatter. Independent outputs.
__global__ __launch_bounds__(256) void stage1_scatter_kernel(
    const float* __restrict__ x, const float* __restrict__ gamma,
    const float* __restrict__ beta, const float* __restrict__ mean,
    const float* __restrict__ var, const float* __restrict__ b1,
    const int* __restrict__ ei)
{
    if (blockIdx.x >= S1BLOCKS) {              // ---- scatter part ----
        int t = (blockIdx.x - S1BLOCKS) * 256 + threadIdx.x;
        int e = t * 4;
        if (e < EE) {
            int4 s4 = *(const int4*)(ei + e);
            int4 d4 = *(const int4*)(ei + EE + e);
            int p;
            p = atomicAdd(&g_cnt[d4.x], 1); if (p < SLOT) g_slots[d4.x * SLOT + p] = s4.x;
            p = atomicAdd(&g_cnt[d4.y], 1); if (p < SLOT) g_slots[d4.y * SLOT + p] = s4.y;
            p = atomicAdd(&g_cnt[d4.z], 1); if (p < SLOT) g_slots[d4.z * SLOT + p] = s4.z;
            p = atomicAdd(&g_cnt[d4.w], 1); if (p < SLOT) g_slots[d4.w * SLOT + p] = s4.w;
        }
        return;
    }
    // ---- stage1 part ----
    __shared__ unsigned short xh[32 * XPITCH];
    __shared__ unsigned short xl[32 * XPITCH];
    __shared__ float s_lds[CIN], t_lds[CIN];
    const int tid = threadIdx.x;
    const int w = tid >> 6, lane = tid & 63;
    const int m = lane & 15, quad = lane >> 4;
    if (tid < CIN) {
        float s = gamma[tid] * rsqrtf(var[tid] + BN_EPS);
        s_lds[tid] = s;
        t_lds[tid] = beta[tid] - mean[tid] * s;
    }
    __syncthreads();
    const int mbase = blockIdx.x * 32;
    #pragma unroll
    for (int it = 0; it < 4; it++) {
        int slot = it * 256 + tid;
        int n = slot >> 5;
        int k = (slot & 31) * 4;
        int node = mbase + n;
        float4 v = make_float4(0.f, 0.f, 0.f, 0.f);
        if (node < NN) v = *(const float4*)(x + (size_t)node * CIN + k);
        float f[4] = {v.x, v.y, v.z, v.w};
        ushort4 uh, ul;
        unsigned short hb;
        float fn;
        fn = f[0] * s_lds[k + 0] + t_lds[k + 0]; hb = f2bf(fn); uh.x = hb; ul.x = f2bf(fn - bf2f(hb));
        fn = f[1] * s_lds[k + 1] + t_lds[k + 1]; hb = f2bf(fn); uh.y = hb; ul.y = f2bf(fn - bf2f(hb));
        fn = f[2] * s_lds[k + 2] + t_lds[k + 2]; hb = f2bf(fn); uh.z = hb; ul.z = f2bf(fn - bf2f(hb));
        fn = f[3] * s_lds[k + 3] + t_lds[k + 3]; hb = f2bf(fn); uh.w = hb; ul.w = f2bf(fn - bf2f(hb));
        *(ushort4*)(xh + n * XPITCH + k) = uh;
        *(ushort4*)(xl + n * XPITCH + k) = ul;
    }
    __syncthreads();

    floatx4 acc[2][8];
    #pragma unroll
    for (int mt = 0; mt < 2; mt++)
        #pragma unroll
        for (int nt = 0; nt < 8; nt++)
            acc[mt][nt] = (floatx4){0.f, 0.f, 0.f, 0.f};

    #pragma unroll
    for (int k0 = 0; k0 < 4; k0++) {
        short8x wf[8];
        #pragma unroll
        for (int nt = 0; nt < 8; nt++) {
            int t = w * 8 + nt;
            wf[nt] = *(const short8x*)(g_W1f + (size_t)((t * 4 + k0) * 64 + lane) * 8);
        }
        #pragma unroll
        for (int mt = 0; mt < 2; mt++) {
            const unsigned short* rp = xh + (mt * 16 + m) * XPITCH + k0 * 32 + quad * 8;
            const unsigned short* lp = xl + (mt * 16 + m) * XPITCH + k0 * 32 + quad * 8;
            short8x ah = *(const short8x*)rp;
            short8x al = *(const short8x*)lp;
            #pragma unroll
            for (int nt = 0; nt < 8; nt++) {
                acc[mt][nt] = __builtin_amdgcn_mfma_f32_16x16x32_bf16(al, wf[nt], acc[mt][nt], 0, 0, 0);
                acc[mt][nt] = __builtin_amdgcn_mfma_f32_16x16x32_bf16(ah, wf[nt], acc[mt][nt], 0, 0, 0);
            }
        }
    }
    const int colbase = w * 128;
    #pragma unroll
    for (int mt = 0; mt < 2; mt++) {
        #pragma unroll
        for (int nt = 0; nt < 8; nt++) {
            int col = colbase + nt * 16 + m;
            #pragma unroll
            for (int j = 0; j < 4; j++) {
                int node = mbase + mt * 16 + quad * 4 + j;
                if (node < NN) {
                    float v = acc[mt][nt][j];
                    if (col < 256) g_A[(size_t)node * HH + col] = v + b1[col];
                    else           g_Bb[(size_t)node * HH + (col - 256)] = f2bf(v);
                }
            }
        }
    }
}

// Main kernel v3: 256 threads = 4 waves; 32-edge periods; 32x32x16 MFMA.
// Wave w = col-group w (cols w*32..w*32+31, full K=256 W2 frags in 64 VGPRs).
// Each wave produces h rows w*8..w*8+7; all 4 waves consume the whole 32-row tile.
// 4-wave blocks place one wave per SIMD -> resident blocks interleave produce(VALU)
// and MFMA phases across blocks. hbuf pitch 528 B (132 words == 4 mod 32): both the
// uint2 producer writes and the b128 A-frag reads land at the wave64 minimum
// (8 lanes per 16B slot) without a staircase term.
__global__ __launch_bounds__(256, 4) void edge_kernel(const float* __restrict__ b2,
                                                      float* __restrict__ out)
{
    __shared__ unsigned short hbuf[32 * HPITCH];   // 16.5 KB
    __shared__ int sbuf[SLOT];
    const int tid = threadIdx.x;
    const int w = tid >> 6, lane = tid & 63;
    const int l31 = lane & 31, half = lane >> 5;
    const unsigned laneoff = (unsigned)lane << 3;  // lane*8 bytes

    // Full-K W2 B-frags for col-group w: 16 x short8x = 64 VGPR.
    short8x bfrag[16];
    #pragma unroll
    for (int k0 = 0; k0 < 16; k0++)
        bfrag[k0] = *(const short8x*)(g_W2f + (size_t)((w * 16 + k0) * 64 + lane) * 8);
    const float b2v = b2[w * 32 + l31];

    for (int g = 0; g < 4; g++) {
        const int node = blockIdx.x * 4 + g;
        int deg = g_cnt[node]; if (deg > SLOT) deg = SLOT;
        const float4 av = *(const float4*)(g_A + (size_t)node * HH + lane * 4);
        if (tid < deg) sbuf[tid] = g_slots[node * SLOT + tid];
        __syncthreads();                  // sbuf ready; prev node done with hbuf
        float rm = -INFINITY;
        if (deg > 0) {
            const int ntp = (deg + 31) >> 5;
            uint2 bv[8];
            #pragma unroll
            for (int q = 0; q < 8; q++) {   // prefetch period 0; rows w*8..w*8+7
                int er = w * 8 + q;
                int sv = (er < deg) ? sbuf[er] : 0;
                bv[q] = *(const uint2*)((const char*)g_Bb + (((unsigned)sv << 9) | laneoff));
            }
            for (int p = 0; p < ntp; p++) {
                const int tb = p << 5;
                #pragma unroll
                for (int q = 0; q < 8; q++) {
                    uint2 b = bv[q];
                    float f0 = __uint_as_float(b.x << 16);
                    float f1 = __uint_as_float(b.x & 0xffff0000u);
                    float f2 = __uint_as_float(b.y << 16);
                    float f3 = __uint_as_float(b.y & 0xffff0000u);
                    uint2 hv;
                    hv.x = pkbf(fmaxf(av.x + f0, 0.f), fmaxf(av.y + f1, 0.f));
                    hv.y = pkbf(fmaxf(av.z + f2, 0.f), fmaxf(av.w + f3, 0.f));
                    *(uint2*)(hbuf + (w * 8 + q) * HPITCH + (lane << 2)) = hv;
                }
                __syncthreads();          // hbuf(p) ready
                if (p + 1 < ntp) {        // prefetch next period during MFMA
                    const int tb2 = tb + 32;
                    #pragma unroll
                    for (int q = 0; q < 8; q++) {
                        int er = tb2 + w * 8 + q;
                        int sv = (er < deg) ? sbuf[er] : 0;
                        bv[q] = *(const uint2*)((const char*)g_Bb + (((unsigned)sv << 9) | laneoff));
                    }
                }
                const unsigned short* ha = hbuf + l31 * HPITCH + (half << 3);
                floatx16 acc;
                #pragma unroll
                for (int j = 0; j < 16; j++) acc[j] = 0.f;
                #pragma unroll
                for (int k0 = 0; k0 < 16; k0++) {
                    short8x af = *(const short8x*)(ha + k0 * 16);
                    acc = __builtin_amdgcn_mfma_f32_32x32x16_bf16(af, bfrag[k0], acc, 0, 0, 0);
                }
                if (tb + 32 <= deg) {
                    #pragma unroll
                    for (int j = 0; j < 16; j++) rm = fmaxf(rm, acc[j]);
                } else {
                    #pragma unroll
                    for (int j = 0; j < 16; j++) {
                        int rr = tb + (j & 3) + ((j >> 2) << 3) + (half << 2);
                        if (rr < deg) rm = fmaxf(rm, acc[j]);
                    }
                }
                __syncthreads();          // all 4 waves done reading hbuf(p)
            }
        }
        // lanes l and l+32 hold the same col, disjoint rows -> one xor-32 combine.
        rm = fmaxf(rm, __shfl_xor(rm, 32));
        if (half == 0)
            out[(size_t)node * COUT + w * 32 + l31] = (deg > 0) ? fmaxf(rm + b2v, 0.f) : 0.f;
    }
}

extern "C" void kernel_launch(void* const* d_in, const int* in_sizes, int n_in,
                              void* d_out, int out_size, void* d_ws, size_t ws_size,
                              hipStream_t stream) {
    const float* x      = (const float*)d_in[0];
    const int*   ei     = (const int*)d_in[1];
    const float* gamma  = (const float*)d_in[2];
    const float* beta   = (const float*)d_in[3];
    const float* mean   = (const float*)d_in[4];
    const float* var    = (const float*)d_in[5];
    const float* W1     = (const float*)d_in[6];
    const float* b1     = (const float*)d_in[7];
    const float* W2     = (const float*)d_in[8];
    const float* b2     = (const float*)d_in[9];
    float* out = (float*)d_out;
    (void)d_ws; (void)ws_size;

    prep_kernel<<<88, 256, 0, stream>>>(W1, W2);
    stage1_scatter_kernel<<<S1BLOCKS + 625, 256, 0, stream>>>(x, gamma, beta, mean, var, b1, ei);
    edge_kernel<<<NN / 4, 256, 0, stream>>>(b2, out);
}